// Round 1
// baseline (44.217 us; speedup 1.0000x reference)
//
#include <hip/hip_runtime.h>
#include <hip/hip_bf16.h>

// DiffJPEG fused kernel for MI355X (gfx950).
// Input : x [16,3,512,512] f32 in [0,1]
// Output: rgb [16,3,512,512] f32
//
// One workgroup = one 16x16 pixel tile = 4 Y blocks + 1 Cb + 1 Cr block.
// 384 threads = 6 waves; wave w owns 8x8 block w (0..3 = Y quadrants, 4 = Cb, 5 = Cr).

#define QUALITY_FACTOR 0.1f   // (200 - 2*95)/100

// Y_TABLE[u][v] = _Y[v][u] (reference transposes _Y)
__device__ static const float YTAB[8][8] = {
    {16, 12, 14, 14, 18, 24, 49, 72},
    {11, 12, 13, 17, 22, 35, 64, 92},
    {10, 14, 16, 22, 37, 55, 78, 95},
    {16, 19, 24, 29, 56, 64, 87, 98},
    {24, 26, 40, 51, 68, 81, 103, 112},
    {40, 58, 57, 87, 109, 104, 121, 100},
    {51, 60, 69, 80, 103, 113, 120, 103},
    {61, 55, 56, 62, 77, 92, 101, 99}};

// C_TABLE: 99 everywhere except [u<4][v<4] = symmetric 4x4 block
__device__ static const float CTAB[8][8] = {
    {17, 18, 24, 47, 99, 99, 99, 99},
    {18, 21, 26, 66, 99, 99, 99, 99},
    {24, 26, 56, 99, 99, 99, 99, 99},
    {47, 66, 99, 99, 99, 99, 99, 99},
    {99, 99, 99, 99, 99, 99, 99, 99},
    {99, 99, 99, 99, 99, 99, 99, 99},
    {99, 99, 99, 99, 99, 99, 99, 99},
    {99, 99, 99, 99, 99, 99, 99, 99}};

// diff_round(x) = x - (1/pi) * sum_{n=1..9} ((-1)^{n+1}/n) sin(2*pi*n*x)
// sin(2*pi*n*x) is 1-periodic in x -> reduce f = x - rint(x), then Chebyshev
// recurrence sin((n+1)t) = 2cos(t) sin(nt) - sin((n-1)t).
__device__ __forceinline__ float diff_round_f(float x) {
    float f = x - rintf(x);                       // |f| <= 0.5
    float th = 6.283185307179586f * f;            // in [-pi, pi]
    float s1, c1;
    __sincosf(th, &s1, &c1);
    float twoc = 2.0f * c1;
    float sprev = 0.0f;   // sin(0*t)
    float scur = s1;      // sin(1*t)
    float s = 0.0f;
    // coefficients (+1, -1/2, +1/3, ..., +1/9)
    const float coef[9] = {1.0f, -0.5f, 1.0f/3.0f, -0.25f, 0.2f,
                           -1.0f/6.0f, 1.0f/7.0f, -0.125f, 1.0f/9.0f};
#pragma unroll
    for (int n = 0; n < 9; ++n) {
        s += coef[n] * scur;
        float snext = twoc * scur - sprev;
        sprev = scur;
        scur = snext;
    }
    return x - s * 0.3183098861837907f;           // 1/pi
}

__global__ __launch_bounds__(384) void diffjpeg_kernel(
        const float* __restrict__ x, float* __restrict__ out) {
    // grid: (1024, 16) -> blockIdx.x = tile index in 32x32 grid, blockIdx.y = batch
    __shared__ float S[6][8][9];     // block scratch (ping)
    __shared__ float T[6][8][9];     // block scratch (pong)
    __shared__ float CbF[16][16];    // full-res chroma before pooling
    __shared__ float CrF[16][16];
    __shared__ float Cm[8][9];       // cos((2x+1)*u*pi/16), Cm[x][u]

    const int tid = threadIdx.x;
    const int bimg = blockIdx.y;
    const int tileY = blockIdx.x >> 5;
    const int tileX = blockIdx.x & 31;
    const int W = 512;
    const size_t plane = (size_t)512 * 512;
    const float* img = x + (size_t)bimg * 3 * plane;
    float* dst = out + (size_t)bimg * 3 * plane;

    if (tid < 64) {
        int xx = tid >> 3, uu = tid & 7;
        Cm[xx][uu] = cosf((2.0f * xx + 1.0f) * uu * 0.19634954084936207f); // pi/16
    }

    const int py = tid >> 4;          // 0..15 (for tid<256)
    const int px = tid & 15;

    // ---- stage 0: pixels -> YCbCr, Y into S blocks, chroma full-res to LDS ----
    if (tid < 256) {
        int row = tileY * 16 + py;
        int col = tileX * 16 + px;
        size_t off = (size_t)row * W + col;
        float r = img[off] * 255.0f;
        float g = img[plane + off] * 255.0f;
        float b = img[2 * plane + off] * 255.0f;
        float yv = 0.299f * r + 0.587f * g + 0.114f * b;
        float cb = -0.168736f * r - 0.331264f * g + 0.5f * b + 128.0f;
        float cr = 0.5f * r - 0.418688f * g - 0.081312f * b + 128.0f;
        int w = ((py >> 3) << 1) | (px >> 3);
        S[w][py & 7][px & 7] = yv - 128.0f;
        CbF[py][px] = cb;
        CrF[py][px] = cr;
    }
    __syncthreads();

    // ---- stage 1: 2x2 avgpool chroma into S[4], S[5] ----
    if (tid < 64) {
        int pr = tid >> 3, pc = tid & 7;
        float cb = 0.25f * (CbF[2*pr][2*pc] + CbF[2*pr][2*pc+1] +
                            CbF[2*pr+1][2*pc] + CbF[2*pr+1][2*pc+1]);
        float cr = 0.25f * (CrF[2*pr][2*pc] + CrF[2*pr][2*pc+1] +
                            CrF[2*pr+1][2*pc] + CrF[2*pr+1][2*pc+1]);
        S[4][pr][pc] = cb - 128.0f;
        S[5][pr][pc] = cr - 128.0f;
    }
    __syncthreads();

    // ---- block transforms: wave w handles block w, lane = (r,c) ----
    const int w = tid >> 6;
    const int lane = tid & 63;
    const int r = lane >> 3;
    const int c = lane & 7;

    // DCT stage 1: tmp[x][v] = sum_y B[x][y] * Cm[y][v]   (lane: x=r, v=c)
    float acc = 0.0f;
#pragma unroll
    for (int yy = 0; yy < 8; ++yy) acc += S[w][r][yy] * Cm[yy][c];
    T[w][r][c] = acc;
    __syncthreads();

    // DCT stage 2 + quant + diff_round + dequant (+ALPHA premul for IDCT)
    // dct[u][v] = 0.25*alpha_u*alpha_v * sum_x Cm[x][u] * tmp[x][v]   (u=r, v=c)
    acc = 0.0f;
#pragma unroll
    for (int xx = 0; xx < 8; ++xx) acc += Cm[xx][r] * T[w][xx][c];
    float au = (r == 0) ? 0.7071067811865476f : 1.0f;
    float av = (c == 0) ? 0.7071067811865476f : 1.0f;
    float dct = 0.25f * au * av * acc;
    float tf = ((w < 4) ? YTAB[r][c] : CTAB[r][c]) * QUALITY_FACTOR;
    float q = diff_round_f(dct / tf);
    float d = q * tf * (au * av);   // dequant * ALPHA (premultiplied for IDCT)
    S[w][r][c] = d;
    __syncthreads();

    // IDCT stage 1: Wm[x][v] = sum_y dA[x][y] * Cm[v][y]   (x=r, v=c)
    acc = 0.0f;
#pragma unroll
    for (int yy = 0; yy < 8; ++yy) acc += S[w][r][yy] * Cm[c][yy];
    T[w][r][c] = acc;
    __syncthreads();

    // IDCT stage 2: out[u][v] = 0.25 * sum_x Cm[u][x] * Wm[x][v] + 128  (u=r, v=c)
    acc = 0.0f;
#pragma unroll
    for (int xx = 0; xx < 8; ++xx) acc += Cm[r][xx] * T[w][xx][c];
    S[w][r][c] = 0.25f * acc + 128.0f;
    __syncthreads();

    // ---- final: upsample chroma (nearest), YCbCr -> RGB, clip, /255, store ----
    if (tid < 256) {
        int row = tileY * 16 + py;
        int col = tileX * 16 + px;
        size_t off = (size_t)row * W + col;
        int w2 = ((py >> 3) << 1) | (px >> 3);
        float yv = S[w2][py & 7][px & 7];
        float cb = S[4][py >> 1][px >> 1] - 128.0f;
        float cr = S[5][py >> 1][px >> 1] - 128.0f;
        float r2 = yv + 1.402f * cr;
        float g2 = yv - 0.344136f * cb - 0.714136f * cr;
        float b2 = yv + 1.772f * cb;
        r2 = fminf(fmaxf(r2, 0.0f), 255.0f) * (1.0f / 255.0f);
        g2 = fminf(fmaxf(g2, 0.0f), 255.0f) * (1.0f / 255.0f);
        b2 = fminf(fmaxf(b2, 0.0f), 255.0f) * (1.0f / 255.0f);
        dst[off] = r2;
        dst[plane + off] = g2;
        dst[2 * plane + off] = b2;
    }
}

extern "C" void kernel_launch(void* const* d_in, const int* in_sizes, int n_in,
                              void* d_out, int out_size, void* d_ws, size_t ws_size,
                              hipStream_t stream) {
    const float* x = (const float*)d_in[0];
    float* out = (float*)d_out;
    dim3 grid(1024, 16);   // 32x32 tiles per image, 16 images
    dim3 block(384);
    diffjpeg_kernel<<<grid, block, 0, stream>>>(x, out);
}

// Round 2
// 34.911 us; speedup vs baseline: 1.2666x; 1.2666x over previous
//
#include <hip/hip_runtime.h>
#include <hip/hip_bf16.h>

// DiffJPEG fused, v2: one thread per 8x8 JPEG block, block kept in VGPRs.
// Workgroup = 64x128 pixel region = 4x8 tiles:
//   tid 0..127  : Y blocks  (8 block-rows x 16 block-cols)
//   tid 128..159: Cb blocks (one per 16x16 tile, 4x8 tiles)
//   tid 160..191: Cr blocks
// Only LDS use: 256-float quant-scale table + decompressed chroma exchange.

__device__ constexpr float YTAB8[8][8] = {   // = _Y transposed (Y_TABLE)
    {16, 12, 14, 14, 18, 24, 49, 72},
    {11, 12, 13, 17, 22, 35, 64, 92},
    {10, 14, 16, 22, 37, 55, 78, 95},
    {16, 19, 24, 29, 56, 64, 87, 98},
    {24, 26, 40, 51, 68, 81, 103, 112},
    {40, 58, 57, 87, 109, 104, 121, 100},
    {51, 60, 69, 80, 103, 113, 120, 103},
    {61, 55, 56, 62, 77, 92, 101, 99}};

__device__ constexpr float CTAB8[8][8] = {
    {17, 18, 24, 47, 99, 99, 99, 99},
    {18, 21, 26, 66, 99, 99, 99, 99},
    {24, 26, 56, 99, 99, 99, 99, 99},
    {47, 66, 99, 99, 99, 99, 99, 99},
    {99, 99, 99, 99, 99, 99, 99, 99},
    {99, 99, 99, 99, 99, 99, 99, 99},
    {99, 99, 99, 99, 99, 99, 99, 99},
    {99, 99, 99, 99, 99, 99, 99, 99}};

#define C1f 0.9807852804032304f
#define C2f 0.9238795325112867f
#define C3f 0.8314696123025452f
#define C4f 0.7071067811865476f
#define C5f 0.5555702330196022f
#define C6f 0.3826834323650898f
#define C7f 0.1950903220161283f

// 8-point DCT-II (unnormalized): X_u = sum_n x_n cos((2n+1)u pi/16)
#define DCT8(x0,x1,x2,x3,x4,x5,x6,x7) do { \
    float e0=(x0)+(x7), e1=(x1)+(x6), e2=(x2)+(x5), e3=(x3)+(x4); \
    float o0=(x0)-(x7), o1=(x1)-(x6), o2=(x2)-(x5), o3=(x3)-(x4); \
    float t0=e0+e3, t1=e1+e2, d0=e0-e3, d1=e1-e2; \
    (x0)=t0+t1; (x4)=(t0-t1)*C4f; \
    (x2)=d0*C2f+d1*C6f; (x6)=d0*C6f-d1*C2f; \
    (x1)=o0*C1f+o1*C3f+o2*C5f+o3*C7f; \
    (x3)=o0*C3f-o1*C7f-o2*C1f-o3*C5f; \
    (x5)=o0*C5f-o1*C1f+o2*C7f+o3*C3f; \
    (x7)=o0*C7f-o1*C5f+o2*C3f-o3*C1f; \
} while(0)

// 8-point DCT-III (unnormalized): x_n = sum_u X_u cos((2n+1)u pi/16)
#define IDCT8(x0,x1,x2,x3,x4,x5,x6,x7) do { \
    float a=(x4)*C4f, p=(x0)+a, m=(x0)-a; \
    float q=(x2)*C2f+(x6)*C6f, w=(x2)*C6f-(x6)*C2f; \
    float E0=p+q, E1=m+w, E2=m-w, E3=p-q; \
    float O0=(x1)*C1f+(x3)*C3f+(x5)*C5f+(x7)*C7f; \
    float O1=(x1)*C3f-(x3)*C7f-(x5)*C1f-(x7)*C5f; \
    float O2=(x1)*C5f-(x3)*C1f+(x5)*C7f+(x7)*C3f; \
    float O3=(x1)*C7f-(x3)*C5f+(x5)*C3f-(x7)*C1f; \
    (x0)=E0+O0; (x7)=E0-O0; (x1)=E1+O1; (x6)=E1-O1; \
    (x2)=E2+O2; (x5)=E2-O2; (x3)=E3+O3; (x4)=E3-O3; \
} while(0)

// diff_round via exact periodic reduction + Chebyshev sin recurrence
__device__ __forceinline__ float diff_round_f(float x) {
    float f = x - rintf(x);
    float th = 6.283185307179586f * f;
    float s1, c1v;
    __sincosf(th, &s1, &c1v);
    float twoc = 2.0f * c1v;
    float sp = 0.0f, sc = s1, acc = 0.0f;
    const float coef[9] = {1.0f, -0.5f, 1.0f/3.0f, -0.25f, 0.2f,
                           -1.0f/6.0f, 1.0f/7.0f, -0.125f, 1.0f/9.0f};
#pragma unroll
    for (int n = 0; n < 9; ++n) {
        acc += coef[n] * sc;
        float sn = twoc * sc - sp;
        sp = sc; sc = sn;
    }
    return x - acc * 0.3183098861837907f;
}

__global__ __launch_bounds__(192) void diffjpeg_kernel(
        const float* __restrict__ x, float* __restrict__ out) {
    __shared__ float QS[2][128];      // interleaved (s1,s2) per (u,v); [0]=Y, [1]=C
    __shared__ float CbL[32][65];     // decompressed chroma (no +128), stride-65 pad
    __shared__ float CrL[32][65];

    const int tid = threadIdx.x;

    // quant/dequant scale tables: s1 = 0.25*au*av/(T*0.1), s2 = 0.25*au*av*(T*0.1)
    if (tid < 128) {
        int type = tid >> 6;               // 0=Y, 1=C
        int k = tid & 63, u = k >> 3, v = k & 7;
        float t = (type ? CTAB8[u][v] : YTAB8[u][v]) * 0.1f;
        float aa = 0.25f * ((u == 0) ? C4f : 1.0f) * ((v == 0) ? C4f : 1.0f);
        QS[type][2 * k]     = aa / t;
        QS[type][2 * k + 1] = aa * t;
    }

    const int img = blockIdx.y;
    const int ry = (blockIdx.x >> 2) * 64;
    const int rx = (blockIdx.x & 3) * 128;
    const size_t plane = (size_t)512 * 512;
    const float* src = x + (size_t)img * 3 * plane;
    float* dst = out + (size_t)img * 3 * plane;

    float y[8][8];
    int py0, px0;

    if (tid < 128) {
        // ---- Y block load + color convert ----
        const int brow = tid >> 4, bcol = tid & 15;
        py0 = ry + brow * 8; px0 = rx + bcol * 8;
#pragma unroll
        for (int r = 0; r < 8; ++r) {
            const float* p = src + (size_t)(py0 + r) * 512 + px0;
            float4 R0 = *(const float4*)(p);
            float4 R1 = *(const float4*)(p + 4);
            float4 G0 = *(const float4*)(p + plane);
            float4 G1 = *(const float4*)(p + plane + 4);
            float4 B0 = *(const float4*)(p + 2 * plane);
            float4 B1 = *(const float4*)(p + 2 * plane + 4);
            y[r][0] = 76.245f * R0.x + 149.685f * G0.x + 29.07f * B0.x - 128.0f;
            y[r][1] = 76.245f * R0.y + 149.685f * G0.y + 29.07f * B0.y - 128.0f;
            y[r][2] = 76.245f * R0.z + 149.685f * G0.z + 29.07f * B0.z - 128.0f;
            y[r][3] = 76.245f * R0.w + 149.685f * G0.w + 29.07f * B0.w - 128.0f;
            y[r][4] = 76.245f * R1.x + 149.685f * G1.x + 29.07f * B1.x - 128.0f;
            y[r][5] = 76.245f * R1.y + 149.685f * G1.y + 29.07f * B1.y - 128.0f;
            y[r][6] = 76.245f * R1.z + 149.685f * G1.z + 29.07f * B1.z - 128.0f;
            y[r][7] = 76.245f * R1.w + 149.685f * G1.w + 29.07f * B1.w - 128.0f;
        }
    } else {
        // ---- chroma block: pool 2x2 RGB then convert (linear => exact) ----
        const int c = tid - 128;
        const int isCr = c >> 5;
        const int t = c & 31;
        py0 = ry + (t >> 3) * 16; px0 = rx + (t & 7) * 16;
        // coeffs * 255/4 (no +-128: the +128 shift and -128 in compress cancel)
        const float kr = isCr ?  31.875f   : -10.75692f;
        const float kg = isCr ? -26.69136f : -21.11808f;
        const float kb = isCr ?  -5.18364f :  31.875f;
#pragma unroll
        for (int pr = 0; pr < 8; ++pr) {
            const float* p0 = src + (size_t)(py0 + 2 * pr) * 512 + px0;
            const float* p1 = p0 + 512;
#pragma unroll
            for (int j = 0; j < 4; ++j) {
                float4 ra = *(const float4*)(p0 + 4 * j);
                float4 rb = *(const float4*)(p1 + 4 * j);
                float4 ga = *(const float4*)(p0 + plane + 4 * j);
                float4 gb = *(const float4*)(p1 + plane + 4 * j);
                float4 ba = *(const float4*)(p0 + 2 * plane + 4 * j);
                float4 bb = *(const float4*)(p1 + 2 * plane + 4 * j);
                float rs0 = ra.x + ra.y + rb.x + rb.y, rs1 = ra.z + ra.w + rb.z + rb.w;
                float gs0 = ga.x + ga.y + gb.x + gb.y, gs1 = ga.z + ga.w + gb.z + gb.w;
                float bs0 = ba.x + ba.y + bb.x + bb.y, bs1 = ba.z + ba.w + bb.z + bb.w;
                y[pr][2 * j]     = kr * rs0 + kg * gs0 + kb * bs0;
                y[pr][2 * j + 1] = kr * rs1 + kg * gs1 + kb * bs1;
            }
        }
    }

    __syncthreads();   // QS table ready

    // ---- forward DCT (rows then cols), all in registers ----
#pragma unroll
    for (int r = 0; r < 8; ++r)
        DCT8(y[r][0], y[r][1], y[r][2], y[r][3], y[r][4], y[r][5], y[r][6], y[r][7]);
#pragma unroll
    for (int cc = 0; cc < 8; ++cc)
        DCT8(y[0][cc], y[1][cc], y[2][cc], y[3][cc], y[4][cc], y[5][cc], y[6][cc], y[7][cc]);

    // ---- quantize + diff_round + dequantize (scales broadcast from LDS) ----
    {
        const float* qs = QS[tid >= 128];
#pragma unroll
        for (int u = 0; u < 8; ++u)
#pragma unroll
            for (int v = 0; v < 8; ++v) {
                float s1v = qs[2 * (u * 8 + v)];
                float s2v = qs[2 * (u * 8 + v) + 1];
                y[u][v] = diff_round_f(y[u][v] * s1v) * s2v;
            }
    }

    // ---- inverse DCT (cols then rows) ----
#pragma unroll
    for (int cc = 0; cc < 8; ++cc)
        IDCT8(y[0][cc], y[1][cc], y[2][cc], y[3][cc], y[4][cc], y[5][cc], y[6][cc], y[7][cc]);
#pragma unroll
    for (int r = 0; r < 8; ++r)
        IDCT8(y[r][0], y[r][1], y[r][2], y[r][3], y[r][4], y[r][5], y[r][6], y[r][7]);

    if (tid >= 128) {
        // chroma: publish decompressed block (without +128) to LDS
        const int c = tid - 128;
        float (*L)[65] = (c >> 5) ? CrL : CbL;
        float* row = L[c & 31];
#pragma unroll
        for (int r = 0; r < 8; ++r)
#pragma unroll
            for (int cc = 0; cc < 8; ++cc)
                row[r * 8 + cc] = y[r][cc];
    }
    __syncthreads();   // chroma ready

    if (tid < 128) {
        const int brow = tid >> 4, bcol = tid & 15;
        const int t = (brow >> 1) * 8 + (bcol >> 1);
        const int lc = (bcol & 1) * 4;
#pragma unroll
        for (int i = 0; i < 8; ++i) {
            const int lr = (brow & 1) * 4 + (i >> 1);
            const float* cbr = &CbL[t][lr * 8 + lc];
            const float* crr = &CrL[t][lr * 8 + lc];
            float oR[8], oG[8], oB[8];
#pragma unroll
            for (int j = 0; j < 8; ++j) {
                float cb = cbr[j >> 1];
                float cr = crr[j >> 1];
                float yv = y[i][j] + 128.0f;
                float R = yv + 1.402f * cr;
                float G = yv - 0.344136f * cb - 0.714136f * cr;
                float B = yv + 1.772f * cb;
                oR[j] = fminf(fmaxf(R, 0.0f), 255.0f) * (1.0f / 255.0f);
                oG[j] = fminf(fmaxf(G, 0.0f), 255.0f) * (1.0f / 255.0f);
                oB[j] = fminf(fmaxf(B, 0.0f), 255.0f) * (1.0f / 255.0f);
            }
            float* p = dst + (size_t)(py0 + i) * 512 + px0;
            *(float4*)(p)                 = make_float4(oR[0], oR[1], oR[2], oR[3]);
            *(float4*)(p + 4)             = make_float4(oR[4], oR[5], oR[6], oR[7]);
            *(float4*)(p + plane)         = make_float4(oG[0], oG[1], oG[2], oG[3]);
            *(float4*)(p + plane + 4)     = make_float4(oG[4], oG[5], oG[6], oG[7]);
            *(float4*)(p + 2 * plane)     = make_float4(oB[0], oB[1], oB[2], oB[3]);
            *(float4*)(p + 2 * plane + 4) = make_float4(oB[4], oB[5], oB[6], oB[7]);
        }
    }
}

extern "C" void kernel_launch(void* const* d_in, const int* in_sizes, int n_in,
                              void* d_out, int out_size, void* d_ws, size_t ws_size,
                              hipStream_t stream) {
    const float* x = (const float*)d_in[0];
    float* out = (float*)d_out;
    dim3 grid(32, 16);   // 8x4 regions of 64x128 px per image, 16 images
    dim3 block(192);
    diffjpeg_kernel<<<grid, block, 0, stream>>>(x, out);
}

// Round 3
// 32.207 us; speedup vs baseline: 1.3729x; 1.0840x over previous
//
#include <hip/hip_runtime.h>
#include <hip/hip_bf16.h>

// DiffJPEG fused, v3: 8 threads per 8x8 block (one per row), shuffle transposes.
// Workgroup = 16x128 pixel strip:
//   tid 0..255  : Y rows.  wave w (0..3), lane = r*8+b: block (w*8+b), row r.
//                 block idx 0..31 -> brow = idx>>4 (0..1), bcol = idx&15.
//   tid 256..319: Cb rows. lane = r*8+b: chroma block b (0..7), pooled row r.
//   tid 320..383: Cr rows.
// Transposes within each wave via __shfl_xor (masks 8/16/32): the 8 threads of
// a block are lanes {r*8+b : r=0..7} for fixed b.
// LDS: quant-scale table (broadcast) + decompressed chroma exchange (padded).

__device__ constexpr float YTAB8[8][8] = {   // = _Y transposed (Y_TABLE)
    {16, 12, 14, 14, 18, 24, 49, 72},
    {11, 12, 13, 17, 22, 35, 64, 92},
    {10, 14, 16, 22, 37, 55, 78, 95},
    {16, 19, 24, 29, 56, 64, 87, 98},
    {24, 26, 40, 51, 68, 81, 103, 112},
    {40, 58, 57, 87, 109, 104, 121, 100},
    {51, 60, 69, 80, 103, 113, 120, 103},
    {61, 55, 56, 62, 77, 92, 101, 99}};

__device__ constexpr float CTAB8[8][8] = {
    {17, 18, 24, 47, 99, 99, 99, 99},
    {18, 21, 26, 66, 99, 99, 99, 99},
    {24, 26, 56, 99, 99, 99, 99, 99},
    {47, 66, 99, 99, 99, 99, 99, 99},
    {99, 99, 99, 99, 99, 99, 99, 99},
    {99, 99, 99, 99, 99, 99, 99, 99},
    {99, 99, 99, 99, 99, 99, 99, 99},
    {99, 99, 99, 99, 99, 99, 99, 99}};

#define C1f 0.9807852804032304f
#define C2f 0.9238795325112867f
#define C3f 0.8314696123025452f
#define C4f 0.7071067811865476f
#define C5f 0.5555702330196022f
#define C6f 0.3826834323650898f
#define C7f 0.1950903220161283f

// 8-point DCT-II (unnormalized): X_u = sum_n x_n cos((2n+1)u pi/16)
__device__ __forceinline__ void dct8(float y[8]) {
    float e0=y[0]+y[7], e1=y[1]+y[6], e2=y[2]+y[5], e3=y[3]+y[4];
    float o0=y[0]-y[7], o1=y[1]-y[6], o2=y[2]-y[5], o3=y[3]-y[4];
    float t0=e0+e3, t1=e1+e2, d0=e0-e3, d1=e1-e2;
    y[0]=t0+t1; y[4]=(t0-t1)*C4f;
    y[2]=d0*C2f+d1*C6f; y[6]=d0*C6f-d1*C2f;
    y[1]=o0*C1f+o1*C3f+o2*C5f+o3*C7f;
    y[3]=o0*C3f-o1*C7f-o2*C1f-o3*C5f;
    y[5]=o0*C5f-o1*C1f+o2*C7f+o3*C3f;
    y[7]=o0*C7f-o1*C5f+o2*C3f-o3*C1f;
}

// 8-point DCT-III (unnormalized): x_n = sum_u X_u cos((2n+1)u pi/16)
__device__ __forceinline__ void idct8(float y[8]) {
    float a=y[4]*C4f, p=y[0]+a, m=y[0]-a;
    float q=y[2]*C2f+y[6]*C6f, w=y[2]*C6f-y[6]*C2f;
    float E0=p+q, E1=m+w, E2=m-w, E3=p-q;
    float O0=y[1]*C1f+y[3]*C3f+y[5]*C5f+y[7]*C7f;
    float O1=y[1]*C3f-y[3]*C7f-y[5]*C1f-y[7]*C5f;
    float O2=y[1]*C5f-y[3]*C1f+y[5]*C7f+y[7]*C3f;
    float O3=y[1]*C7f-y[3]*C5f+y[5]*C3f-y[7]*C1f;
    y[0]=E0+O0; y[7]=E0-O0; y[1]=E1+O1; y[6]=E1-O1;
    y[2]=E2+O2; y[5]=E2-O2; y[3]=E3+O3; y[4]=E3-O3;
}

// 8x8 transpose across the 8 threads (lane bits 3..5) holding one block.
__device__ __forceinline__ void transpose8(float y[8]) {
    const int lane = threadIdx.x & 63;
#pragma unroll
    for (int s = 1; s <= 4; s <<= 1) {
        const bool upper = (lane & (s << 3)) != 0;
#pragma unroll
        for (int j = 0; j < 8; ++j) {
            if ((j & s) == 0) {
                float a = y[j], b = y[j | s];
                float t = upper ? a : b;
                t = __shfl_xor(t, s << 3, 64);
                if (upper) y[j] = t; else y[j | s] = t;
            }
        }
    }
}

// diff_round via exact periodic reduction + Chebyshev sin recurrence
__device__ __forceinline__ float diff_round_f(float x) {
    float f = x - rintf(x);
    float th = 6.283185307179586f * f;
    float s1, c1v;
    __sincosf(th, &s1, &c1v);
    float twoc = 2.0f * c1v;
    float sp = 0.0f, sc = s1, acc = 0.0f;
    const float coef[9] = {1.0f, -0.5f, 1.0f/3.0f, -0.25f, 0.2f,
                           -1.0f/6.0f, 1.0f/7.0f, -0.125f, 1.0f/9.0f};
#pragma unroll
    for (int n = 0; n < 9; ++n) {
        acc += coef[n] * sc;
        float sn = twoc * sc - sp;
        sp = sc; sc = sn;
    }
    return x - acc * 0.3183098861837907f;
}

__global__ __launch_bounds__(384, 8) void diffjpeg_kernel(
        const float* __restrict__ x, float* __restrict__ out) {
    __shared__ float QS[2][128];      // interleaved (s1,s2); [0]=Y, [1]=C
    __shared__ float CL[2][8][72];    // chroma exchange: [ch][block][row*9+col]

    const int tid = threadIdx.x;

    // quant/dequant scales: s1 = 0.25*au*av/(T*0.1), s2 = 0.25*au*av*(T*0.1)
    if (tid < 128) {
        int type = tid >> 6;
        int k = tid & 63, u = k >> 3, v = k & 7;
        float t = (type ? CTAB8[u][v] : YTAB8[u][v]) * 0.1f;
        float aa = 0.25f * ((u == 0) ? C4f : 1.0f) * ((v == 0) ? C4f : 1.0f);
        QS[type][2 * k]     = aa / t;
        QS[type][2 * k + 1] = aa * t;
    }

    const int img = blockIdx.y;
    const int sy = (blockIdx.x >> 2) * 16;    // strip: 16 rows x 128 cols
    const int sx = (blockIdx.x & 3) * 128;
    const size_t plane = (size_t)512 * 512;
    const float* src = x + (size_t)img * 3 * plane;
    float* dst = out + (size_t)img * 3 * plane;

    const int lane = tid & 63;
    const int r = lane >> 3;      // row within block / transpose-group index
    const int b = lane & 7;

    float y[8];
    int brow = 0, bcol = 0;       // Y only

    if (tid < 256) {
        // ---- Y: one pixel row of one 8x8 block ----
        const int blk = (tid >> 6) * 8 + b;
        brow = blk >> 4; bcol = blk & 15;
        const int py = sy + brow * 8 + r;
        const int px = sx + bcol * 8;
        const float* p = src + (size_t)py * 512 + px;
        float4 R0 = *(const float4*)(p);
        float4 R1 = *(const float4*)(p + 4);
        float4 G0 = *(const float4*)(p + plane);
        float4 G1 = *(const float4*)(p + plane + 4);
        float4 B0 = *(const float4*)(p + 2 * plane);
        float4 B1 = *(const float4*)(p + 2 * plane + 4);
        y[0] = 76.245f * R0.x + 149.685f * G0.x + 29.07f * B0.x - 128.0f;
        y[1] = 76.245f * R0.y + 149.685f * G0.y + 29.07f * B0.y - 128.0f;
        y[2] = 76.245f * R0.z + 149.685f * G0.z + 29.07f * B0.z - 128.0f;
        y[3] = 76.245f * R0.w + 149.685f * G0.w + 29.07f * B0.w - 128.0f;
        y[4] = 76.245f * R1.x + 149.685f * G1.x + 29.07f * B1.x - 128.0f;
        y[5] = 76.245f * R1.y + 149.685f * G1.y + 29.07f * B1.y - 128.0f;
        y[6] = 76.245f * R1.z + 149.685f * G1.z + 29.07f * B1.z - 128.0f;
        y[7] = 76.245f * R1.w + 149.685f * G1.w + 29.07f * B1.w - 128.0f;
    } else {
        // ---- chroma: one pooled row (8 vals) from 2x16 px, 3 channels ----
        const int isCr = (tid >= 320);
        const float kr = isCr ?  31.875f   : -10.75692f;   // coeff * 255/4
        const float kg = isCr ? -26.69136f : -21.11808f;
        const float kb = isCr ?  -5.18364f :  31.875f;
        const int py = sy + 2 * r;
        const int px = sx + b * 16;
        const float* p0 = src + (size_t)py * 512 + px;
        const float* p1 = p0 + 512;
#pragma unroll 1
        for (int j = 0; j < 4; ++j) {
            float4 ra = *(const float4*)(p0 + 4 * j);
            float4 rb = *(const float4*)(p1 + 4 * j);
            float4 ga = *(const float4*)(p0 + plane + 4 * j);
            float4 gb = *(const float4*)(p1 + plane + 4 * j);
            float4 ba = *(const float4*)(p0 + 2 * plane + 4 * j);
            float4 bb = *(const float4*)(p1 + 2 * plane + 4 * j);
            float rs0 = ra.x + ra.y + rb.x + rb.y, rs1 = ra.z + ra.w + rb.z + rb.w;
            float gs0 = ga.x + ga.y + gb.x + gb.y, gs1 = ga.z + ga.w + gb.z + gb.w;
            float bs0 = ba.x + ba.y + bb.x + bb.y, bs1 = ba.z + ba.w + bb.z + bb.w;
            y[2 * j]     = kr * rs0 + kg * gs0 + kb * bs0;
            y[2 * j + 1] = kr * rs1 + kg * gs1 + kb * bs1;
        }
    }

    // ---- forward DCT: rows, transpose, rows ----
    dct8(y);
    transpose8(y);
    dct8(y);

    __syncthreads();   // QS ready

    // thread now holds D(u=j, v=r) of its block
    {
        const float* qs = QS[tid >= 256];
#pragma unroll
        for (int j = 0; j < 8; ++j) {
            float s1v = qs[2 * (j * 8 + r)];
            float s2v = qs[2 * (j * 8 + r) + 1];
            y[j] = diff_round_f(y[j] * s1v) * s2v;
        }
    }

    // ---- inverse DCT ----
    idct8(y);
    transpose8(y);
    idct8(y);
    // thread holds spatial row r of its decompressed block (no +128 yet)

    if (tid >= 256) {
        const int ch = (tid >= 320);
        float* row = &CL[ch][b][r * 9];
#pragma unroll
        for (int j = 0; j < 8; ++j) row[j] = y[j];
    }
    __syncthreads();   // chroma ready

    if (tid < 256) {
        const int cbB = bcol >> 1;
        const int pr = (brow * 8 + r) >> 1;
        const int lc = (bcol & 1) * 4;
        const float* cbr = &CL[0][cbB][pr * 9 + lc];
        const float* crr = &CL[1][cbB][pr * 9 + lc];
        float cb0 = cbr[0], cb1 = cbr[1], cb2 = cbr[2], cb3 = cbr[3];
        float cr0 = crr[0], cr1 = crr[1], cr2 = crr[2], cr3 = crr[3];
        float oR[8], oG[8], oB[8];
        const float cbs[8] = {cb0, cb0, cb1, cb1, cb2, cb2, cb3, cb3};
        const float crs[8] = {cr0, cr0, cr1, cr1, cr2, cr2, cr3, cr3};
#pragma unroll
        for (int j = 0; j < 8; ++j) {
            float yv = y[j] + 128.0f;
            float R = yv + 1.402f * crs[j];
            float G = yv - 0.344136f * cbs[j] - 0.714136f * crs[j];
            float B = yv + 1.772f * cbs[j];
            oR[j] = fminf(fmaxf(R, 0.0f), 255.0f) * (1.0f / 255.0f);
            oG[j] = fminf(fmaxf(G, 0.0f), 255.0f) * (1.0f / 255.0f);
            oB[j] = fminf(fmaxf(B, 0.0f), 255.0f) * (1.0f / 255.0f);
        }
        const int py = sy + brow * 8 + r;
        const int px = sx + bcol * 8;
        float* p = dst + (size_t)py * 512 + px;
        *(float4*)(p)                 = make_float4(oR[0], oR[1], oR[2], oR[3]);
        *(float4*)(p + 4)             = make_float4(oR[4], oR[5], oR[6], oR[7]);
        *(float4*)(p + plane)         = make_float4(oG[0], oG[1], oG[2], oG[3]);
        *(float4*)(p + plane + 4)     = make_float4(oG[4], oG[5], oG[6], oG[7]);
        *(float4*)(p + 2 * plane)     = make_float4(oB[0], oB[1], oB[2], oB[3]);
        *(float4*)(p + 2 * plane + 4) = make_float4(oB[4], oB[5], oB[6], oB[7]);
    }
}

extern "C" void kernel_launch(void* const* d_in, const int* in_sizes, int n_in,
                              void* d_out, int out_size, void* d_ws, size_t ws_size,
                              hipStream_t stream) {
    const float* x = (const float*)d_in[0];
    float* out = (float*)d_out;
    dim3 grid(128, 16);   // 32x4 strips of 16x128 px per image, 16 images
    dim3 block(384);
    diffjpeg_kernel<<<grid, block, 0, stream>>>(x, out);
}

// Round 4
// 25.544 us; speedup vs baseline: 1.7310x; 1.2608x over previous
//
#include <hip/hip_runtime.h>
#include <hip/hip_bf16.h>

// DiffJPEG fused, v4: uniform 256-thread blocks, one thread per Y block-row.
// Strip = 16x128 px. Phases:
//   P0: load RGB (Y threads only source of global reads), convert to y[8],
//       pool 2x2 RGB sums via shfl_xor(8), publish pooled sums to LDS.
//   P1: Y DCT -> quant/diff_round -> IDCT, publish y+128 rows to LDS.
//   P2: tid<128: chroma rows from pooled sums -> DCT -> quant -> IDCT -> LDS.
//   P3: all 256 threads combine + store all 3 planes, coalesced float4.
// 2 barriers. Global traffic = exactly 50 MB in + 50 MB out.

__device__ constexpr float YTAB8[8][8] = {   // = _Y transposed (Y_TABLE)
    {16, 12, 14, 14, 18, 24, 49, 72},
    {11, 12, 13, 17, 22, 35, 64, 92},
    {10, 14, 16, 22, 37, 55, 78, 95},
    {16, 19, 24, 29, 56, 64, 87, 98},
    {24, 26, 40, 51, 68, 81, 103, 112},
    {40, 58, 57, 87, 109, 104, 121, 100},
    {51, 60, 69, 80, 103, 113, 120, 103},
    {61, 55, 56, 62, 77, 92, 101, 99}};

__device__ constexpr float CTAB8[8][8] = {
    {17, 18, 24, 47, 99, 99, 99, 99},
    {18, 21, 26, 66, 99, 99, 99, 99},
    {24, 26, 56, 99, 99, 99, 99, 99},
    {47, 66, 99, 99, 99, 99, 99, 99},
    {99, 99, 99, 99, 99, 99, 99, 99},
    {99, 99, 99, 99, 99, 99, 99, 99},
    {99, 99, 99, 99, 99, 99, 99, 99},
    {99, 99, 99, 99, 99, 99, 99, 99}};

#define C1f 0.9807852804032304f
#define C2f 0.9238795325112867f
#define C3f 0.8314696123025452f
#define C4f 0.7071067811865476f
#define C5f 0.5555702330196022f
#define C6f 0.3826834323650898f
#define C7f 0.1950903220161283f

__device__ __forceinline__ void dct8(float y[8]) {
    float e0=y[0]+y[7], e1=y[1]+y[6], e2=y[2]+y[5], e3=y[3]+y[4];
    float o0=y[0]-y[7], o1=y[1]-y[6], o2=y[2]-y[5], o3=y[3]-y[4];
    float t0=e0+e3, t1=e1+e2, d0=e0-e3, d1=e1-e2;
    y[0]=t0+t1; y[4]=(t0-t1)*C4f;
    y[2]=d0*C2f+d1*C6f; y[6]=d0*C6f-d1*C2f;
    y[1]=o0*C1f+o1*C3f+o2*C5f+o3*C7f;
    y[3]=o0*C3f-o1*C7f-o2*C1f-o3*C5f;
    y[5]=o0*C5f-o1*C1f+o2*C7f+o3*C3f;
    y[7]=o0*C7f-o1*C5f+o2*C3f-o3*C1f;
}

__device__ __forceinline__ void idct8(float y[8]) {
    float a=y[4]*C4f, p=y[0]+a, m=y[0]-a;
    float q=y[2]*C2f+y[6]*C6f, w=y[2]*C6f-y[6]*C2f;
    float E0=p+q, E1=m+w, E2=m-w, E3=p-q;
    float O0=y[1]*C1f+y[3]*C3f+y[5]*C5f+y[7]*C7f;
    float O1=y[1]*C3f-y[3]*C7f-y[5]*C1f-y[7]*C5f;
    float O2=y[1]*C5f-y[3]*C1f+y[5]*C7f+y[7]*C3f;
    float O3=y[1]*C7f-y[3]*C5f+y[5]*C3f-y[7]*C1f;
    y[0]=E0+O0; y[7]=E0-O0; y[1]=E1+O1; y[6]=E1-O1;
    y[2]=E2+O2; y[5]=E2-O2; y[3]=E3+O3; y[4]=E3-O3;
}

// 8x8 transpose across the 8 threads (lane bits 3..5) holding one block.
__device__ __forceinline__ void transpose8(float y[8]) {
    const int lane = threadIdx.x & 63;
#pragma unroll
    for (int s = 1; s <= 4; s <<= 1) {
        const bool upper = (lane & (s << 3)) != 0;
#pragma unroll
        for (int j = 0; j < 8; ++j) {
            if ((j & s) == 0) {
                float a = y[j], b2 = y[j | s];
                float t = upper ? a : b2;
                t = __shfl_xor(t, s << 3, 64);
                if (upper) y[j] = t; else y[j | s] = t;
            }
        }
    }
}

__device__ __forceinline__ float diff_round_f(float x) {
    float f = x - rintf(x);
    float th = 6.283185307179586f * f;
    float s1, c1v;
    __sincosf(th, &s1, &c1v);
    float twoc = 2.0f * c1v;
    float sp = 0.0f, sc = s1, acc = 0.0f;
    const float coef[9] = {1.0f, -0.5f, 1.0f/3.0f, -0.25f, 0.2f,
                           -1.0f/6.0f, 1.0f/7.0f, -0.125f, 1.0f/9.0f};
#pragma unroll
    for (int n = 0; n < 9; ++n) {
        acc += coef[n] * sc;
        float sn = twoc * sc - sp;
        sp = sc; sc = sn;
    }
    return x - acc * 0.3183098861837907f;
}

__global__ __launch_bounds__(256, 6) void diffjpeg_kernel(
        const float* __restrict__ x, float* __restrict__ out) {
    __shared__ float QS[2][128];      // (s1,s2) interleaved; [0]=Y, [1]=C
    __shared__ float PL[3][8][68];    // pooled RGB sums [ch][prow][pcol]
    __shared__ float YL[16][132];     // decompressed Y + 128
    __shared__ float CL[2][8][68];    // decompressed chroma (cb-128 form)

    const int tid = threadIdx.x;
    const int lane = tid & 63;
    const int r = lane >> 3;
    const int b = lane & 7;

    if (tid < 128) {
        int type = tid >> 6;
        int k = tid & 63, u = k >> 3, v = k & 7;
        float t = (type ? CTAB8[u][v] : YTAB8[u][v]) * 0.1f;
        float aa = 0.25f * ((u == 0) ? C4f : 1.0f) * ((v == 0) ? C4f : 1.0f);
        QS[type][2 * k]     = aa / t;
        QS[type][2 * k + 1] = aa * t;
    }

    const int img = blockIdx.y;
    const int sy = (blockIdx.x >> 2) * 16;
    const int sx = (blockIdx.x & 3) * 128;
    const size_t plane = (size_t)512 * 512;
    const float* src = x + (size_t)img * 3 * plane;
    float* dst = out + (size_t)img * 3 * plane;

    // ---- P0: load one Y block-row, convert, pool ----
    const int blkY = (tid >> 6) * 8 + b;
    const int brow = blkY >> 4, bcol = blkY & 15;
    float y[8];
    {
        const int py = sy + brow * 8 + r;
        const int px = sx + bcol * 8;
        const float* p = src + (size_t)py * 512 + px;
        float4 R0 = *(const float4*)(p);
        float4 R1 = *(const float4*)(p + 4);
        float4 G0 = *(const float4*)(p + plane);
        float4 G1 = *(const float4*)(p + plane + 4);
        float4 B0 = *(const float4*)(p + 2 * plane);
        float4 B1 = *(const float4*)(p + 2 * plane + 4);
        y[0] = 76.245f * R0.x + 149.685f * G0.x + 29.07f * B0.x - 128.0f;
        y[1] = 76.245f * R0.y + 149.685f * G0.y + 29.07f * B0.y - 128.0f;
        y[2] = 76.245f * R0.z + 149.685f * G0.z + 29.07f * B0.z - 128.0f;
        y[3] = 76.245f * R0.w + 149.685f * G0.w + 29.07f * B0.w - 128.0f;
        y[4] = 76.245f * R1.x + 149.685f * G1.x + 29.07f * B1.x - 128.0f;
        y[5] = 76.245f * R1.y + 149.685f * G1.y + 29.07f * B1.y - 128.0f;
        y[6] = 76.245f * R1.z + 149.685f * G1.z + 29.07f * B1.z - 128.0f;
        y[7] = 76.245f * R1.w + 149.685f * G1.w + 29.07f * B1.w - 128.0f;
        // horizontal 2-px sums, then vertical pair add via shfl (rows r, r^1)
        float rs0 = R0.x + R0.y, rs1 = R0.z + R0.w, rs2 = R1.x + R1.y, rs3 = R1.z + R1.w;
        float gs0 = G0.x + G0.y, gs1 = G0.z + G0.w, gs2 = G1.x + G1.y, gs3 = G1.z + G1.w;
        float bs0 = B0.x + B0.y, bs1 = B0.z + B0.w, bs2 = B1.x + B1.y, bs3 = B1.z + B1.w;
        rs0 += __shfl_xor(rs0, 8, 64); rs1 += __shfl_xor(rs1, 8, 64);
        rs2 += __shfl_xor(rs2, 8, 64); rs3 += __shfl_xor(rs3, 8, 64);
        gs0 += __shfl_xor(gs0, 8, 64); gs1 += __shfl_xor(gs1, 8, 64);
        gs2 += __shfl_xor(gs2, 8, 64); gs3 += __shfl_xor(gs3, 8, 64);
        bs0 += __shfl_xor(bs0, 8, 64); bs1 += __shfl_xor(bs1, 8, 64);
        bs2 += __shfl_xor(bs2, 8, 64); bs3 += __shfl_xor(bs3, 8, 64);
        if (!(r & 1)) {
            const int prow = brow * 4 + (r >> 1);
            const int pc = bcol * 4;
            *(float4*)&PL[0][prow][pc] = make_float4(rs0, rs1, rs2, rs3);
            *(float4*)&PL[1][prow][pc] = make_float4(gs0, gs1, gs2, gs3);
            *(float4*)&PL[2][prow][pc] = make_float4(bs0, bs1, bs2, bs3);
        }
    }
    __syncthreads();   // PL + QS ready

    // ---- P1: Y transform ----
    dct8(y); transpose8(y); dct8(y);
    {
        const float* qs = QS[0];
#pragma unroll
        for (int j = 0; j < 8; ++j) {
            float s1v = qs[2 * (j * 8 + r)];
            float s2v = qs[2 * (j * 8 + r) + 1];
            y[j] = diff_round_f(y[j] * s1v) * s2v;
        }
    }
    idct8(y); transpose8(y); idct8(y);
    {
        const int row = brow * 8 + r;
        *(float4*)&YL[row][bcol * 8]     = make_float4(y[0]+128.f, y[1]+128.f, y[2]+128.f, y[3]+128.f);
        *(float4*)&YL[row][bcol * 8 + 4] = make_float4(y[4]+128.f, y[5]+128.f, y[6]+128.f, y[7]+128.f);
    }

    // ---- P2: chroma pipeline on tid<128 (r = pooled row, b = chroma block) ----
    if (tid < 128) {
        const int ch = tid >> 6;          // 0=Cb, 1=Cr
        const float kr = ch ?  31.875f   : -10.75692f;   // coeff * 255/4
        const float kg = ch ? -26.69136f : -21.11808f;
        const float kb = ch ?  -5.18364f :  31.875f;
        float c[8];
        {
            float4 ra = *(const float4*)&PL[0][r][b * 8];
            float4 rb2 = *(const float4*)&PL[0][r][b * 8 + 4];
            float4 ga = *(const float4*)&PL[1][r][b * 8];
            float4 gb2 = *(const float4*)&PL[1][r][b * 8 + 4];
            float4 ba = *(const float4*)&PL[2][r][b * 8];
            float4 bb2 = *(const float4*)&PL[2][r][b * 8 + 4];
            c[0] = kr * ra.x + kg * ga.x + kb * ba.x;
            c[1] = kr * ra.y + kg * ga.y + kb * ba.y;
            c[2] = kr * ra.z + kg * ga.z + kb * ba.z;
            c[3] = kr * ra.w + kg * ga.w + kb * ba.w;
            c[4] = kr * rb2.x + kg * gb2.x + kb * bb2.x;
            c[5] = kr * rb2.y + kg * gb2.y + kb * bb2.y;
            c[6] = kr * rb2.z + kg * gb2.z + kb * bb2.z;
            c[7] = kr * rb2.w + kg * gb2.w + kb * bb2.w;
        }
        dct8(c); transpose8(c); dct8(c);
        {
            const float* qs = QS[1];
#pragma unroll
            for (int j = 0; j < 8; ++j) {
                float s1v = qs[2 * (j * 8 + r)];
                float s2v = qs[2 * (j * 8 + r) + 1];
                c[j] = diff_round_f(c[j] * s1v) * s2v;
            }
        }
        idct8(c); transpose8(c); idct8(c);
        *(float4*)&CL[ch][r][b * 8]     = make_float4(c[0], c[1], c[2], c[3]);
        *(float4*)&CL[ch][r][b * 8 + 4] = make_float4(c[4], c[5], c[6], c[7]);
    }
    __syncthreads();   // YL + CL ready

    // ---- P3: combine + store, all threads, channel-uniform per iteration ----
#pragma unroll
    for (int k = 0; k < 6; ++k) {
        const int ch = k >> 1;
        const int rem = ((k & 1) << 8) | tid;     // 0..511
        const int row = rem >> 5;                 // 0..15
        const int col = (rem & 31) * 4;           // 0..124
        float4 y4 = *(const float4*)&YL[row][col];
        const int prow = row >> 1, pc = col >> 1;
        float cb0 = CL[0][prow][pc],     cb1 = CL[0][prow][pc + 1];
        float cr0 = CL[1][prow][pc],     cr1 = CL[1][prow][pc + 1];
        float o[4];
        if (ch == 0) {
            o[0] = y4.x + 1.402f * cr0; o[1] = y4.y + 1.402f * cr0;
            o[2] = y4.z + 1.402f * cr1; o[3] = y4.w + 1.402f * cr1;
        } else if (ch == 1) {
            o[0] = y4.x - 0.344136f * cb0 - 0.714136f * cr0;
            o[1] = y4.y - 0.344136f * cb0 - 0.714136f * cr0;
            o[2] = y4.z - 0.344136f * cb1 - 0.714136f * cr1;
            o[3] = y4.w - 0.344136f * cb1 - 0.714136f * cr1;
        } else {
            o[0] = y4.x + 1.772f * cb0; o[1] = y4.y + 1.772f * cb0;
            o[2] = y4.z + 1.772f * cb1; o[3] = y4.w + 1.772f * cb1;
        }
#pragma unroll
        for (int j = 0; j < 4; ++j)
            o[j] = fminf(fmaxf(o[j], 0.0f), 255.0f) * (1.0f / 255.0f);
        float* p = dst + (size_t)ch * plane + (size_t)(sy + row) * 512 + sx + col;
        *(float4*)p = make_float4(o[0], o[1], o[2], o[3]);
    }
}

extern "C" void kernel_launch(void* const* d_in, const int* in_sizes, int n_in,
                              void* d_out, int out_size, void* d_ws, size_t ws_size,
                              hipStream_t stream) {
    const float* x = (const float*)d_in[0];
    float* out = (float*)d_out;
    dim3 grid(128, 16);   // 32x4 strips of 16x128 px per image, 16 images
    dim3 block(256);
    diffjpeg_kernel<<<grid, block, 0, stream>>>(x, out);
}